// Round 3
// baseline (270.555 us; speedup 1.0000x reference)
//
#include <hip/hip_runtime.h>
#include <stdint.h>

typedef __attribute__((ext_vector_type(8))) short short8;
typedef __attribute__((ext_vector_type(4))) float floatx4;
typedef __attribute__((ext_vector_type(16))) float floatx16;
typedef __attribute__((ext_vector_type(2))) unsigned int uintx2;
typedef unsigned short u16;
typedef unsigned int u32;

#define EDIM 128
#define FDIM 512
#define BM 64
#define QSTR (EDIM + 8)   // 136 bf16 = 272 B row stride (16B aligned)
#define HSTR (128 + 8)    // 136 bf16
#define NTILE 2048
#define GRID 512          // persistent blocks; each handles exactly 4 tiles

// round-to-nearest-even float -> bf16 (prep path)
__device__ __forceinline__ u32 f2bf_rne(float f) {
    u32 u = __builtin_bit_cast(u32, f);
    return (u + 0x7fffu + ((u >> 16) & 1u)) >> 16;
}
__device__ __forceinline__ u32 pk2bf(float lo, float hi) {
    return f2bf_rne(lo) | (f2bf_rne(hi) << 16);
}
// HW packed f32x2 -> bf16x2, RNE (main path)
__device__ __forceinline__ u32 cvtpk(float lo, float hi) {
    u32 r;
    asm("v_cvt_pk_bf16_f32 %0, %1, %2" : "=v"(r) : "v"(lo), "v"(hi));
    return r;
}

// Pre-swizzle W1/W2 to bf16 in MFMA A-fragment lane order:
//   W1s group g  = ft*512 + k*64 + lane   (16B per group)
//        holds W1[ft*32 + (lane&31)][k*16 + (lane>>5)*8 + j], j=0..7
//   W2s group g2 = (et*4+c)*512 + k*64 + lane
//        holds W2[et*32 + (lane&31)][c*128 + k*16 + (lane>>5)*8 + j]
// Also: cth[e] = cos(theta[e]) as f32 at wb + 2*FDIM*EDIM (u16 offset).
__global__ __launch_bounds__(256) void ffq_prep(const float* __restrict__ W1,
                                                const float* __restrict__ W2,
                                                const float* __restrict__ theta,
                                                u16* __restrict__ wb) {
    int g = blockIdx.x * 256 + threadIdx.x;   // 0..16383
    int lane = g & 63;
    int kk = (g >> 6) & 7;
    int idx = (g >> 9) & 15;
    int l31 = lane & 31, h5 = lane >> 5;
    if (g < 128) {
        float* cth = reinterpret_cast<float*>(wb + 2 * FDIM * EDIM);
        cth[g] = cosf(theta[g]);
    }
    const float* src;
    if (g < 8192) {
        src = W1 + (idx * 32 + l31) * EDIM + kk * 16 + h5 * 8;
    } else {
        int gg = idx >> 2, c = idx & 3;
        src = W2 + (gg * 32 + l31) * FDIM + c * 128 + kk * 16 + h5 * 8;
    }
    float4 v0 = *reinterpret_cast<const float4*>(src);
    float4 v1 = *reinterpret_cast<const float4*>(src + 4);
    uint4 p;
    p.x = pk2bf(v0.x, v0.y);
    p.y = pk2bf(v0.z, v0.w);
    p.z = pk2bf(v1.x, v1.y);
    p.w = pk2bf(v1.z, v1.w);
    reinterpret_cast<uint4*>(wb)[g] = p;
}

// Fused q = cos(x)*cos(theta); h = relu(q@W1^T); out = h@W2^T.
// Round-0 structure (verified): 64 rows/tile, 8 waves, h through LDS dbuf,
// 1 barrier per f-chunk. New: persistent blocks grid-striding over 4 tiles,
// with next tile's x loads issued into registers right after the staging
// barrier so HBM latency hides under the current tile's 64 MFMAs (T14).
// q B-fragments hoisted to registers once per tile.
__global__ __launch_bounds__(512, 4) void ffq_main(const float* __restrict__ x,
                                                   const u16* __restrict__ wb,
                                                   float* __restrict__ out) {
    __shared__ u16 qs[BM * QSTR];       // 17408 B
    __shared__ u16 hs[2][BM * HSTR];    // 34816 B (total 52224 B)

    const int t = threadIdx.x;
    const int lane = t & 63;
    const int wv = t >> 6;        // wave id 0..7
    const int l31 = lane & 31;
    const int h5 = lane >> 5;     // half-wave 0/1
    const int mg = wv & 1;        // m-group: rows mg*32..mg*32+31
    const int gg = wv >> 1;       // f-group (GEMM1) / e-group (GEMM2): 0..3

    const u16* W1s = wb;
    const u16* W2s = wb + FDIM * EDIM;
    const float* cth = reinterpret_cast<const float*>(wb + 2 * FDIM * EDIM);

    const int et = (t & 31) * 4;  // e offset; same each r since 512 % 32 == 0
    const float c0 = cth[et + 0];
    const float c1 = cth[et + 1];
    const float c2 = cth[et + 2];
    const float c3 = cth[et + 3];

    const u16* w1l = W1s + lane * 8;
    const u16* w2l = W2s + lane * 8;
    const u16* qp  = &qs[(mg * 32 + l31) * QSTR + h5 * 8];

    // ---- preload tile 0's x into registers ----
    float4 xv[4];
    {
        const float4* xin = reinterpret_cast<const float4*>(x) +
                            (size_t)blockIdx.x * (BM * EDIM / 4);
        #pragma unroll
        for (int r = 0; r < 4; ++r) xv[r] = xin[t + 512 * r];
    }

    for (int tile = blockIdx.x; tile < NTILE; tile += GRID) {
        // ---- stage q = cos(x)*cos(theta) into LDS (bf16) from regs ----
        #pragma unroll
        for (int r = 0; r < 4; ++r) {
            int m = (t + 512 * r) >> 5;   // row 0..63
            float4 v = xv[r];
            uintx2 p;
            p.x = pk2bf(__cosf(v.x) * c0, __cosf(v.y) * c1);
            p.y = pk2bf(__cosf(v.z) * c2, __cosf(v.w) * c3);
            *reinterpret_cast<uintx2*>(&qs[m * QSTR + et]) = p;
        }
        __syncthreads();

        // ---- prefetch next tile's x (in flight across the MFMA work) ----
        if (tile + GRID < NTILE) {
            const float4* xin = reinterpret_cast<const float4*>(x) +
                                (size_t)(tile + GRID) * (BM * EDIM / 4);
            #pragma unroll
            for (int r = 0; r < 4; ++r) xv[r] = xin[t + 512 * r];
        }

        // ---- hoist q B-fragments into registers (one read per tile) ----
        // qf[k] element j = q[mg*32 + l31][e = k*16 + h5*8 + j]
        short8 qf[8];
        #pragma unroll
        for (int k = 0; k < 8; ++k)
            qf[k] = *reinterpret_cast<const short8*>(qp + k * 16);

        floatx16 acc2 = {0.f,0.f,0.f,0.f,0.f,0.f,0.f,0.f,
                         0.f,0.f,0.f,0.f,0.f,0.f,0.f,0.f};  // out^T 32x32 tile

        #pragma unroll
        for (int c = 0; c < 4; ++c) {
            // ---- GEMM1: h^T 32x32 tile = W1_tile x q^T, K = 128 ----
            floatx16 acc1 = {0.f,0.f,0.f,0.f,0.f,0.f,0.f,0.f,
                             0.f,0.f,0.f,0.f,0.f,0.f,0.f,0.f};
            const u16* w1p = w1l + (size_t)(c * 4 + gg) * 4096;
            #pragma unroll
            for (int k = 0; k < 8; ++k) {
                short8 a = *reinterpret_cast<const short8*>(w1p + k * 512);
                acc1 = __builtin_amdgcn_mfma_f32_32x32x16_bf16(a, qf[k], acc1, 0, 0, 0);
            }

            // relu + bf16 -> h buffer. D: col m=l31, row f=(reg&3)+8*(reg>>2)+4*h5
            u16* hb = hs[c & 1];
            const int hrow = (mg * 32 + l31) * HSTR;
            #pragma unroll
            for (int rq = 0; rq < 4; ++rq) {
                const int fl = gg * 32 + rq * 8 + h5 * 4;
                uintx2 p;
                p.x = cvtpk(fmaxf(acc1[rq * 4 + 0], 0.f), fmaxf(acc1[rq * 4 + 1], 0.f));
                p.y = cvtpk(fmaxf(acc1[rq * 4 + 2], 0.f), fmaxf(acc1[rq * 4 + 3], 0.f));
                *reinterpret_cast<uintx2*>(&hb[hrow + fl]) = p;
            }
            __syncthreads();   // the only barrier this chunk

            // ---- GEMM2: out^T 32x32 tile += W2_tile x h^T, chunk K = 128 ----
            const u16* w2p = w2l + (size_t)(gg * 4 + c) * 4096;
            const u16* hpc = &hs[c & 1][(mg * 32 + l31) * HSTR + h5 * 8];
            #pragma unroll
            for (int k = 0; k < 8; ++k) {
                short8 a = *reinterpret_cast<const short8*>(w2p + k * 512);
                short8 b = *reinterpret_cast<const short8*>(hpc + k * 16);
                acc2 = __builtin_amdgcn_mfma_f32_32x32x16_bf16(a, b, acc2, 0, 0, 0);
            }
        }

        // ---- epilogue: D col m=l31, row e=gg*32+(reg&3)+8*(reg>>2)+4*h5 ----
        float* op = out + (size_t)tile * BM * EDIM +
                    (mg * 32 + l31) * EDIM + gg * 32 + h5 * 4;
        #pragma unroll
        for (int rq = 0; rq < 4; ++rq) {
            floatx4 v;
            v[0] = acc2[rq * 4 + 0];
            v[1] = acc2[rq * 4 + 1];
            v[2] = acc2[rq * 4 + 2];
            v[3] = acc2[rq * 4 + 3];
            *reinterpret_cast<floatx4*>(op + rq * 8) = v;
        }
    }
}

extern "C" void kernel_launch(void* const* d_in, const int* in_sizes, int n_in,
                              void* d_out, int out_size, void* d_ws, size_t ws_size,
                              hipStream_t stream) {
    const float* x     = (const float*)d_in[0];  // [32,4096,128]
    const float* theta = (const float*)d_in[1];  // [128]
    const float* W1    = (const float*)d_in[2];  // [512,128]
    const float* W2    = (const float*)d_in[3];  // [128,512]
    u16* wb    = (u16*)d_ws;                     // 256 KB bf16 weights + cos(theta) table
    float* out = (float*)d_out;                  // [32,4096,128]

    ffq_prep<<<64, 256, 0, stream>>>(W1, W2, theta, wb);
    ffq_main<<<GRID, 512, 0, stream>>>(x, wb, out);
}

// Round 4
// 181.489 us; speedup vs baseline: 1.4908x; 1.4908x over previous
//
#include <hip/hip_runtime.h>
#include <stdint.h>

typedef __attribute__((ext_vector_type(8))) short short8;
typedef __attribute__((ext_vector_type(4))) float floatx4;
typedef __attribute__((ext_vector_type(16))) float floatx16;
typedef __attribute__((ext_vector_type(2))) unsigned int uintx2;
typedef __attribute__((ext_vector_type(4))) unsigned int uintx4;
typedef unsigned short u16;
typedef unsigned int u32;

#define EDIM 128
#define FDIM 512
#define BM 32             // rows per block
#define HSTR (128 + 8)    // h row stride in bf16 (272 B, 16B aligned)

// round-to-nearest-even float -> bf16 (prep path)
__device__ __forceinline__ u32 f2bf_rne(float f) {
    u32 u = __builtin_bit_cast(u32, f);
    return (u + 0x7fffu + ((u >> 16) & 1u)) >> 16;
}
__device__ __forceinline__ u32 pk2bf(float lo, float hi) {
    return f2bf_rne(lo) | (f2bf_rne(hi) << 16);
}
// HW packed f32x2 -> bf16x2, RNE (main path)
__device__ __forceinline__ u32 cvtpk(float lo, float hi) {
    u32 r;
    asm("v_cvt_pk_bf16_f32 %0, %1, %2" : "=v"(r) : "v"(lo), "v"(hi));
    return r;
}

// Pre-swizzle W1/W2 to bf16 in MFMA A-fragment lane order:
//   W1s group g  = ft*512 + k*64 + lane   (16B per group)
//        holds W1[ft*32 + (lane&31)][k*16 + (lane>>5)*8 + j], j=0..7
//   W2s group g2 = (et*4+c)*512 + k*64 + lane
//        holds W2[et*32 + (lane&31)][c*128 + k*16 + (lane>>5)*8 + j]
// Also: cth[e] = cos(theta[e]) as f32 at wb + 2*FDIM*EDIM (u16 offset).
__global__ __launch_bounds__(256) void ffq_prep(const float* __restrict__ W1,
                                                const float* __restrict__ W2,
                                                const float* __restrict__ theta,
                                                u16* __restrict__ wb) {
    int g = blockIdx.x * 256 + threadIdx.x;   // 0..16383
    int lane = g & 63;
    int kk = (g >> 6) & 7;
    int idx = (g >> 9) & 15;
    int l31 = lane & 31, h5 = lane >> 5;
    if (g < 128) {
        float* cth = reinterpret_cast<float*>(wb + 2 * FDIM * EDIM);
        cth[g] = cosf(theta[g]);
    }
    const float* src;
    if (g < 8192) {
        src = W1 + (idx * 32 + l31) * EDIM + kk * 16 + h5 * 8;
    } else {
        int gg = idx >> 2, c = idx & 3;
        src = W2 + (gg * 32 + l31) * FDIM + c * 128 + kk * 16 + h5 * 8;
    }
    float4 v0 = *reinterpret_cast<const float4*>(src);
    float4 v1 = *reinterpret_cast<const float4*>(src + 4);
    uint4 p;
    p.x = pk2bf(v0.x, v0.y);
    p.y = pk2bf(v0.z, v0.w);
    p.z = pk2bf(v1.x, v1.y);
    p.w = pk2bf(v1.z, v1.w);
    reinterpret_cast<uint4*>(wb)[g] = p;
}

// Fused q = cos(x)*cos(theta); h = relu(q@W1^T); out = h@W2^T.
// 32 rows/block, 4 waves (gg = f-group for GEMM1 / e-group for GEMM2).
// q B-fragments are built DIRECTLY from global x in each wave (no staging
// LDS, no staging barrier) — cos work is duplicated 4x but memory issue is
// decoupled from compute. h goes through a small LDS double buffer with one
// barrier per 128-f chunk (round-0 verified scheme, mg removed).
__global__ __launch_bounds__(256, 4) void ffq_main(const float* __restrict__ x,
                                                   const u16* __restrict__ wb,
                                                   float* __restrict__ out) {
    __shared__ u16 hs[2][BM * HSTR];    // 2 x 8704 B = 17408 B

    const int t = threadIdx.x;
    const int lane = t & 63;
    const int gg = t >> 6;        // wave id 0..3
    const int l31 = lane & 31;
    const int h5 = lane >> 5;     // half-wave 0/1

    const u16* W1s = wb;
    const u16* W2s = wb + FDIM * EDIM;
    const float* cth = reinterpret_cast<const float*>(wb + 2 * FDIM * EDIM);

    // ---- build q B-fragments straight from global x (round-1 verified) ----
    // qf[k] element j = q[T*32 + l31][e = k*16 + h5*8 + j]
    short8 qf[8];
    {
        const float* xr = x + ((size_t)blockIdx.x * BM + l31) * EDIM + h5 * 8;
        const float* tr = cth + h5 * 8;
        #pragma unroll
        for (int k = 0; k < 8; ++k) {
            float4 x0 = *reinterpret_cast<const float4*>(xr + k * 16);
            float4 x1 = *reinterpret_cast<const float4*>(xr + k * 16 + 4);
            float4 t0 = *reinterpret_cast<const float4*>(tr + k * 16);
            float4 t1 = *reinterpret_cast<const float4*>(tr + k * 16 + 4);
            uintx4 u;
            u[0] = cvtpk(__cosf(x0.x) * t0.x, __cosf(x0.y) * t0.y);
            u[1] = cvtpk(__cosf(x0.z) * t0.z, __cosf(x0.w) * t0.w);
            u[2] = cvtpk(__cosf(x1.x) * t1.x, __cosf(x1.y) * t1.y);
            u[3] = cvtpk(__cosf(x1.z) * t1.z, __cosf(x1.w) * t1.w);
            qf[k] = __builtin_bit_cast(short8, u);
        }
    }

    floatx16 acc2 = {0.f,0.f,0.f,0.f,0.f,0.f,0.f,0.f,
                     0.f,0.f,0.f,0.f,0.f,0.f,0.f,0.f};  // out^T 32x32 tile

    const u16* w1l = W1s + lane * 8;
    const u16* w2l = W2s + lane * 8;
    const u16* hpr = &hs[0][l31 * HSTR + h5 * 8];   // read base, buffer 0

    #pragma unroll
    for (int c = 0; c < 4; ++c) {
        // ---- GEMM1: h^T 32x32 tile = W1_tile x q^T, K = 128 ----
        floatx16 acc1 = {0.f,0.f,0.f,0.f,0.f,0.f,0.f,0.f,
                         0.f,0.f,0.f,0.f,0.f,0.f,0.f,0.f};
        const u16* w1p = w1l + (size_t)(c * 4 + gg) * 4096;
        #pragma unroll
        for (int k = 0; k < 8; ++k) {
            short8 a = *reinterpret_cast<const short8*>(w1p + k * 512);
            acc1 = __builtin_amdgcn_mfma_f32_32x32x16_bf16(a, qf[k], acc1, 0, 0, 0);
        }

        // relu + bf16 -> h buffer. D: col m=l31, row f=(reg&3)+8*(reg>>2)+4*h5
        u16* hb = hs[c & 1];
        const int hrow = l31 * HSTR;
        #pragma unroll
        for (int rq = 0; rq < 4; ++rq) {
            const int fl = gg * 32 + rq * 8 + h5 * 4;
            uintx2 p;
            p.x = cvtpk(fmaxf(acc1[rq * 4 + 0], 0.f), fmaxf(acc1[rq * 4 + 1], 0.f));
            p.y = cvtpk(fmaxf(acc1[rq * 4 + 2], 0.f), fmaxf(acc1[rq * 4 + 3], 0.f));
            *reinterpret_cast<uintx2*>(&hb[hrow + fl]) = p;
        }
        __syncthreads();   // the only barrier this chunk

        // ---- GEMM2: out^T 32x32 tile += W2_tile x h^T, chunk K = 128 ----
        const u16* w2p = w2l + (size_t)(gg * 4 + c) * 4096;
        const u16* hpc = hpr + (c & 1) * (BM * HSTR);
        #pragma unroll
        for (int k = 0; k < 8; ++k) {
            short8 a = *reinterpret_cast<const short8*>(w2p + k * 512);
            short8 b = *reinterpret_cast<const short8*>(hpc + k * 16);
            acc2 = __builtin_amdgcn_mfma_f32_32x32x16_bf16(a, b, acc2, 0, 0, 0);
        }
    }

    // ---- epilogue: D col m=l31, row e=gg*32+(reg&3)+8*(reg>>2)+4*h5 ----
    float* op = out + ((size_t)blockIdx.x * BM + l31) * EDIM + gg * 32 + h5 * 4;
    #pragma unroll
    for (int rq = 0; rq < 4; ++rq) {
        floatx4 v;
        v[0] = acc2[rq * 4 + 0];
        v[1] = acc2[rq * 4 + 1];
        v[2] = acc2[rq * 4 + 2];
        v[3] = acc2[rq * 4 + 3];
        *reinterpret_cast<floatx4*>(op + rq * 8) = v;
    }
}

extern "C" void kernel_launch(void* const* d_in, const int* in_sizes, int n_in,
                              void* d_out, int out_size, void* d_ws, size_t ws_size,
                              hipStream_t stream) {
    const float* x     = (const float*)d_in[0];  // [32,4096,128]
    const float* theta = (const float*)d_in[1];  // [128]
    const float* W1    = (const float*)d_in[2];  // [512,128]
    const float* W2    = (const float*)d_in[3];  // [128,512]
    u16* wb    = (u16*)d_ws;                     // 256 KB bf16 weights + cos(theta) table
    float* out = (float*)d_out;                  // [32,4096,128]

    ffq_prep<<<64, 256, 0, stream>>>(W1, W2, theta, wb);
    ffq_main<<<4096, 256, 0, stream>>>(x, wb, out);
}